// Round 8
// baseline (79.017 us; speedup 1.0000x reference)
//
#include <hip/hip_runtime.h>
#include <hip/hip_bf16.h>

#define NB 8
#define NC 512
#define NT 1024
#define NHEADS 8
#define NCH 64
#define NGROUPS 32
#define NGC 16   // channels per group

typedef __attribute__((ext_vector_type(4))) unsigned short u16x4;
typedef __attribute__((ext_vector_type(8))) unsigned short u16x8;
typedef __attribute__((ext_vector_type(4))) float f32x4;
typedef __attribute__((ext_vector_type(8))) __bf16 bfv8;

// hardware f32->bf16 RNE (single v_cvt op; compiler packs pairs to v_cvt_pk_bf16_f32)
static __device__ __forceinline__ unsigned short f2bf(float f) {
    __bf16 h = (__bf16)f;
    return __builtin_bit_cast(unsigned short, h);
}

static __device__ __forceinline__ f32x4 mfma_bf16(u16x8 a, u16x8 b, f32x4 c) {
    return __builtin_amdgcn_mfma_f32_16x16x32_bf16(
        __builtin_bit_cast(bfv8, a), __builtin_bit_cast(bfv8, b), c, 0, 0, 0);
}

// async global->LDS, 16B per lane; dest is wave-uniform base + lane*16
static __device__ __forceinline__ void gl_lds16(const unsigned short* g, unsigned short* l) {
    __builtin_amdgcn_global_load_lds(
        (const __attribute__((address_space(1))) unsigned int*)g,
        (__attribute__((address_space(3))) unsigned int*)l, 16, 0, 0);
}

// ---------------- K1: GroupNorm (blocks 0..255) + w1 cvt (blocks 256..447) ----------------
__global__ __launch_bounds__(512) void k_gn_w1(const float* __restrict__ x,
                                               const float* __restrict__ gw,
                                               const float* __restrict__ gb,
                                               const float* __restrict__ w1,
                                               unsigned short* __restrict__ xnT,
                                               unsigned short* __restrict__ w1b) {
    int tid = threadIdx.x;
    if (blockIdx.x >= 256) {   // w1 fp32 -> bf16
        int i = ((blockIdx.x - 256) * 512 + tid) * 8;
        f32x4 a = *(const f32x4*)(w1 + i);
        f32x4 b = *(const f32x4*)(w1 + i + 4);
        u16x8 o;
#pragma unroll
        for (int j = 0; j < 4; ++j) { o[j] = f2bf(a[j]); o[4 + j] = f2bf(b[j]); }
        *(u16x8*)(w1b + i) = o;
        return;
    }
    int b = blockIdx.x >> 5, g = blockIdx.x & 31;
    int half = tid >> 8, tl = tid & 255;
    int t4 = tl * 4;
    const float* xb = x + ((size_t)(b * NC + g * NGC + half * 8)) * NT;

    f32x4 vv[8];
    float s = 0.f, ss = 0.f;
#pragma unroll
    for (int cc = 0; cc < 8; ++cc) {
        f32x4 v = *(const f32x4*)(xb + cc * NT + t4);
        vv[cc] = v;
#pragma unroll
        for (int i = 0; i < 4; ++i) { s += v[i]; ss += v[i] * v[i]; }
    }
#pragma unroll
    for (int off = 1; off < 64; off <<= 1) { s += __shfl_xor(s, off); ss += __shfl_xor(ss, off); }
    __shared__ float rs_[8], rss[8];
    int w = tid >> 6;
    if ((tid & 63) == 0) { rs_[w] = s; rss[w] = ss; }
    __syncthreads();
    s = 0.f; ss = 0.f;
#pragma unroll
    for (int i = 0; i < 8; ++i) { s += rs_[i]; ss += rss[i]; }
    float mu  = s * (1.f / 16384.f);
    float var = ss * (1.f / 16384.f) - mu * mu;
    float rstd = rsqrtf(var + 1e-5f);

    float wgt[8], bia[8];
#pragma unroll
    for (int cc = 0; cc < 8; ++cc) {
        float ww = gw[g * NGC + half * 8 + cc] * rstd;
        wgt[cc] = ww;
        bia[cc] = gb[g * NGC + half * 8 + cc] - mu * ww;
    }
#pragma unroll
    for (int i = 0; i < 4; ++i) {
        unsigned short o[8];
#pragma unroll
        for (int cc = 0; cc < 8; ++cc) o[cc] = f2bf(vv[cc][i] * wgt[cc] + bia[cc]);
        unsigned short* dst = xnT + ((size_t)(b * NT + t4 + i)) * NC + g * NGC + half * 8;
        *(u16x8*)dst = *(u16x8*)o;
    }
}

// ---------------- K2: QKV GEMM (BK=32, 32KB LDS -> 4 blocks/CU) ----------------
// 128x128 tile, BK=32 double-buffered, global_load_lds staging.
// 64B LDS rows; swizzle slot' = slot ^ ((row>>1)&3) -> column frag reads hit all
// 8 LDS 16B-granules exactly 2x (2-way = free). Source pre-swizzled (involution).
// Epilogue writes q_t/k_t [b][h][t][c] (8B packed stores) and v natural [b][vc][t].
// q scale folds ch^-0.5 (0.125) AND log2(e) so attention uses raw v_exp (exp2).
__global__ __launch_bounds__(256) void k_qkv_gemm(const unsigned short* __restrict__ w1b,
                                                  const unsigned short* __restrict__ xnT,
                                                  const float* __restrict__ b1,
                                                  unsigned short* __restrict__ q_t,
                                                  unsigned short* __restrict__ k_t,
                                                  unsigned short* __restrict__ vbuf) {
    __shared__ unsigned short As[2 * 128 * 32];   // 16KB
    __shared__ unsigned short Bs[2 * 128 * 32];   // 16KB
    int bid = blockIdx.x;
    int lbid = (bid & 7) * 96 + (bid >> 3);   // XCD x owns batch x (768 = 8*96, bijective)
    int bb = lbid / 96;
    int rr_ = lbid % 96;
    int tm = rr_ >> 3, tn = rr_ & 7;
    int tid = threadIdx.x;
    int l = tid & 63, w = tid >> 6;
    int wm = w >> 1, wn = w & 1;
    int ll = l & 15, lg = l >> 4;

    const unsigned short* Ag = w1b + (size_t)(tm * 128) * NC;
    const unsigned short* Bg = xnT + (size_t)(bb * NT + tn * 128) * NC;

    // staging: lane l covers row l>>2, 16B-slot (l&3); source col pre-swizzled
    int srow = l >> 2;
    int sslot = (l & 3) ^ ((l >> 3) & 3);   // == (l&3) ^ ((row>>1)&3)

    auto STAGE = [&](int k0, int buf) {
        unsigned short* dA = As + buf * 4096 + w * 1024;
        unsigned short* dB = Bs + buf * 4096 + w * 1024;
#pragma unroll
        for (int i = 0; i < 2; ++i) {
            int row = w * 32 + i * 16 + srow;
            gl_lds16(Ag + (size_t)row * NC + k0 + sslot * 8, dA + i * 512);
            gl_lds16(Bg + (size_t)row * NC + k0 + sslot * 8, dB + i * 512);
        }
    };

    f32x4 acc[4][4] = {};
    STAGE(0, 0);
    __syncthreads();
    int cur = 0;
    int rsw = (ll >> 1) & 3;   // read-side swizzle == (row>>1)&3 for row = 16m+ll
    for (int ks = 0; ks < 16; ++ks) {
        if (ks < 15) STAGE((ks + 1) * 32, cur ^ 1);
        const char* Ac = (const char*)(As + cur * 4096);
        const char* Bc = (const char*)(Bs + cur * 4096);
        u16x8 af[4], bf[4];
#pragma unroll
        for (int m = 0; m < 4; ++m) {
            int row = wm * 64 + m * 16 + ll;
            af[m] = *(const u16x8*)(Ac + row * 64 + ((lg ^ rsw) * 16));
        }
#pragma unroll
        for (int n = 0; n < 4; ++n) {
            int row = wn * 64 + n * 16 + ll;
            bf[n] = *(const u16x8*)(Bc + row * 64 + ((lg ^ rsw) * 16));
        }
#pragma unroll
        for (int m = 0; m < 4; ++m)
#pragma unroll
            for (int n = 0; n < 4; ++n)
                acc[m][n] = mfma_bf16(af[m], bf[n], acc[m][n]);
        __syncthreads();
        cur ^= 1;
    }

    if (tm < 8) {   // q or k: write [b][h][t][c]
        int qk = tm >> 2;
        int h = (tm & 3) * 2 + wm;
        float sc = qk ? 1.f : 0.125f * 1.44269504088896f;  // q: ch^-0.5 * log2(e)
        int obase = tm * 128 + wm * 64;
        unsigned short* dst = (qk ? k_t : q_t) + ((size_t)(bb * 8 + h)) * NT * NCH;
#pragma unroll
        for (int m = 0; m < 4; ++m) {
#pragma unroll
            for (int n = 0; n < 4; ++n) {
                int t = tn * 128 + wn * 64 + n * 16 + ll;
                u16x4 pk;
#pragma unroll
                for (int r = 0; r < 4; ++r)
                    pk[r] = f2bf((acc[m][n][r] + b1[obase + m * 16 + lg * 4 + r]) * sc);
                *(u16x4*)(dst + (size_t)t * NCH + m * 16 + lg * 4) = pk;
            }
        }
    } else {        // v: natural [b][vc][t]
        int vcb = (tm - 8) * 128 + wm * 64;
#pragma unroll
        for (int m = 0; m < 4; ++m)
#pragma unroll
            for (int r = 0; r < 4; ++r) {
                int vc = vcb + m * 16 + lg * 4 + r;
                float bias = b1[1024 + vc];
#pragma unroll
                for (int n = 0; n < 4; ++n) {
                    int t = tn * 128 + wn * 64 + n * 16 + ll;
                    vbuf[(size_t)(bb * NC + vc) * NT + t] = f2bf(acc[m][n][r] + bias);
                }
            }
    }
}

// ---------------- K3: attention v6 (swapped-QK; V direct from L2, no V staging) ----------------
// block = (b, h, 128-query tile); 4 waves x 32 q-rows. K 64-key tiles double-buffered
// via global_load_lds (source-swizzled). V frags read straight from L2 (vbuf [vc][t]
// is already the PV B-frag layout; per-XCD V = 1MB, L2-resident).
// LDS 32KB -> 4 blocks/CU. No max subtraction; softmax = exp2(S')/rowsum.
#define SW1B(r) (((r) & 7) << 4)                          // K/O row swizzle (128B rows)
__global__ __launch_bounds__(256) void k_attn(const unsigned short* __restrict__ q_t,
                                              const unsigned short* __restrict__ k_t,
                                              const unsigned short* __restrict__ vbuf,
                                              const float* __restrict__ x,
                                              float* __restrict__ out) {
    __shared__ unsigned char smem[32768];
    unsigned short* sK = (unsigned short*)smem;            // [2][64][64] bf16, 16KB
    unsigned short* sP = (unsigned short*)(smem + 16384);  // [4][32][64] bf16, 16KB

    int lbid = ((blockIdx.x & 7) << 6) | (blockIdx.x >> 3);  // XCD x hosts batch x
    int b  = lbid >> 6;
    int h  = (lbid >> 3) & 7;
    int qt = lbid & 7;
    int t0 = qt * 128;

    int tid = threadIdx.x;
    int l = tid & 63, w = tid >> 6;
    int ll = l & 15, lg = l >> 4;
    int rl = l >> 3, sl = l & 7;
    int ssl = sl ^ rl;

    const unsigned short* Qg = q_t + ((size_t)((b * 8 + h) * NT + t0 + w * 32)) * NCH;
    const unsigned short* Kg = k_t + ((size_t)(b * 8 + h)) * NT * NCH;
    const unsigned short* Vg = vbuf + ((size_t)(b * NC + h * NCH)) * NT;

    u16x8 aq[2][2];
#pragma unroll
    for (int m = 0; m < 2; ++m)
#pragma unroll
        for (int kk = 0; kk < 2; ++kk)
            aq[m][kk] = *(const u16x8*)(Qg + (m * 16 + ll) * NCH + kk * 32 + lg * 8);

    f32x4 acc_o[2][4] = {};
    float rs[2] = {};

    auto STAGE = [&](int s0, int buf) {
        unsigned short* dK = sK + buf * 4096 + w * 1024;
#pragma unroll
        for (int i = 0; i < 2; ++i) {
            int row = w * 16 + i * 8 + rl;    // row&7 == rl
            gl_lds16(Kg + (size_t)(s0 + row) * NCH + ssl * 8, dK + i * 512);
        }
    };

    STAGE(0, 0);
    __syncthreads();

    char* sPw = (char*)(sP + w * 2048);   // per-wave [32 t][64 s] bf16 (4KB)
    int cur = 0;
    for (int tile = 0; tile < 16; ++tile) {
        if (tile < 15) STAGE((tile + 1) * 64, cur ^ 1);
        const char* Kc = (const char*)(sK + cur * 4096);
        const unsigned short* Vt = Vg + tile * 64;   // V columns for this tile

        // V frags straight from L2 (no P dependence -> issued early, latency hidden)
        u16x8 bv[4][2];
#pragma unroll
        for (int n = 0; n < 4; ++n)
#pragma unroll
            for (int kk = 0; kk < 2; ++kk)
                bv[n][kk] = *(const u16x8*)(Vt + (size_t)(n * 16 + ll) * NT + kk * 32 + lg * 8);

        // S^T = K Q^T  (swapped operands): lane holds col t = m*16+ll, rows s = j*16+lg*4+r
        f32x4 sc_[2][4];
#pragma unroll
        for (int j = 0; j < 4; ++j) {
            int row = j * 16 + ll;
            int sw = SW1B(row);
            u16x8 b0 = *(const u16x8*)(Kc + row * 128 + ((lg * 16) ^ sw));
            u16x8 b1v = *(const u16x8*)(Kc + row * 128 + ((64 + lg * 16) ^ sw));
            f32x4 z = {0.f, 0.f, 0.f, 0.f};
            sc_[0][j] = mfma_bf16(b1v, aq[0][1], mfma_bf16(b0, aq[0][0], z));
            sc_[1][j] = mfma_bf16(b1v, aq[1][1], mfma_bf16(b0, aq[1][0], z));
        }

        // P = exp2(S); 4 consecutive s per reg -> packed 8B write; scalar rowsum
#pragma unroll
        for (int m = 0; m < 2; ++m) {
            int t = m * 16 + ll;
            int sw = (t & 7) << 4;
#pragma unroll
            for (int j = 0; j < 4; ++j) {
                float p0 = __builtin_amdgcn_exp2f(sc_[m][j][0]);
                float p1 = __builtin_amdgcn_exp2f(sc_[m][j][1]);
                float p2 = __builtin_amdgcn_exp2f(sc_[m][j][2]);
                float p3 = __builtin_amdgcn_exp2f(sc_[m][j][3]);
                rs[m] += (p0 + p1) + (p2 + p3);
                u16x4 pk = {f2bf(p0), f2bf(p1), f2bf(p2), f2bf(p3)};
                *(u16x4*)(sPw + t * 128 + ((j * 32 + lg * 8) ^ sw)) = pk;
            }
        }

        // O += P V^T  (D[t 32][c 64]); P reads == A-frag layout directly
        u16x8 ap[2][2];
#pragma unroll
        for (int m = 0; m < 2; ++m) {
            int t = m * 16 + ll;
            int sw = (t & 7) << 4;
#pragma unroll
            for (int kk = 0; kk < 2; ++kk)
                ap[m][kk] = *(const u16x8*)(sPw + t * 128 + ((kk * 64 + lg * 16) ^ sw));
        }
#pragma unroll
        for (int n = 0; n < 4; ++n)
#pragma unroll
            for (int kk = 0; kk < 2; ++kk) {
                acc_o[0][n] = mfma_bf16(ap[0][kk], bv[n][kk], acc_o[0][n]);
                acc_o[1][n] = mfma_bf16(ap[1][kk], bv[n][kk], acc_o[1][n]);
            }
        __syncthreads();   // drains K staging + guards buffer swap
        cur ^= 1;
    }

    // rowsum: lane holds rs for t = m*16+ll; reduce across the 4 lg replicas
    float rinv[2][4];
#pragma unroll
    for (int m = 0; m < 2; ++m) {
        float s = rs[m];
        s += __shfl_xor(s, 16);
        s += __shfl_xor(s, 32);
        // redistribute to PV-accumulator lanes: t = m*16 + lg*4 + r lives at ll = lg*4+r
#pragma unroll
        for (int r = 0; r < 4; ++r)
            rinv[m][r] = 1.f / __shfl(s, (l & 48) + lg * 4 + r);
    }

    // epilogue: O -> per-wave LDS [c 64][t 32] f32 (swizzled), then coalesced out+residual
    char* sO = (char*)(smem + w * 8192);   // reuses sK/sP (all waves past last read)
#pragma unroll
    for (int m = 0; m < 2; ++m)
#pragma unroll
        for (int n = 0; n < 4; ++n) {
            int c = n * 16 + ll;
            f32x4 o4;
#pragma unroll
            for (int r = 0; r < 4; ++r) o4[r] = acc_o[m][n][r] * rinv[m][r];
            *(f32x4*)(sO + c * 128 + ((m * 64 + lg * 16) ^ SW1B(c))) = o4;
        }
#pragma unroll
    for (int i2 = 0; i2 < 8; ++i2) {
        int c = i2 * 8 + rl;
        f32x4 o4 = *(const f32x4*)(sO + c * 128 + ((sl * 16) ^ SW1B(c)));
        size_t gidx = ((size_t)(b * NC + h * NCH + c)) * NT + t0 + w * 32 + sl * 4;
        f32x4 xv = *(const f32x4*)(x + gidx);
#pragma unroll
        for (int q = 0; q < 4; ++q) o4[q] += xv[q];
        *(f32x4*)(out + gidx) = o4;
    }
}

extern "C" void kernel_launch(void* const* d_in, const int* in_sizes, int n_in,
                              void* d_out, int out_size, void* d_ws, size_t ws_size,
                              hipStream_t stream) {
    (void)in_sizes; (void)n_in; (void)out_size; (void)ws_size;
    const float* x  = (const float*)d_in[0];
    const float* gw = (const float*)d_in[1];
    const float* gb = (const float*)d_in[2];
    const float* w1 = (const float*)d_in[3];
    const float* b1 = (const float*)d_in[4];
    float* out = (float*)d_out;

    char* ws = (char*)d_ws;
    unsigned short* w1b  = (unsigned short*)(ws);                        // 1.5 MB
    unsigned short* xnT  = (unsigned short*)(ws + (size_t)(2u << 20));   // 8.39 MB
    unsigned short* q_t  = (unsigned short*)(ws + (size_t)(11u << 20));  // 8.39 MB
    unsigned short* k_t  = (unsigned short*)(ws + (size_t)(20u << 20));  // 8.39 MB
    unsigned short* vbuf = (unsigned short*)(ws + (size_t)(29u << 20));  // 8.39 MB

    k_gn_w1<<<dim3(448), dim3(512), 0, stream>>>(x, gw, gb, w1, xnT, w1b);
    k_qkv_gemm<<<dim3(768), dim3(256), 0, stream>>>(w1b, xnT, b1, q_t, k_t, vbuf);
    k_attn<<<dim3(512), dim3(256), 0, stream>>>(q_t, k_t, vbuf, x, out);
}

// Round 9
// 75.166 us; speedup vs baseline: 1.0512x; 1.0512x over previous
//
#include <hip/hip_runtime.h>
#include <hip/hip_bf16.h>

#define NB 8
#define NC 512
#define NT 1024
#define NHEADS 8
#define NCH 64
#define NGROUPS 32
#define NGC 16   // channels per group

typedef __attribute__((ext_vector_type(4))) unsigned short u16x4;
typedef __attribute__((ext_vector_type(8))) unsigned short u16x8;
typedef __attribute__((ext_vector_type(4))) float f32x4;
typedef __attribute__((ext_vector_type(8))) __bf16 bfv8;

// hardware f32->bf16 RNE (single v_cvt op; compiler packs pairs to v_cvt_pk_bf16_f32)
static __device__ __forceinline__ unsigned short f2bf(float f) {
    __bf16 h = (__bf16)f;
    return __builtin_bit_cast(unsigned short, h);
}

static __device__ __forceinline__ f32x4 mfma_bf16(u16x8 a, u16x8 b, f32x4 c) {
    return __builtin_amdgcn_mfma_f32_16x16x32_bf16(
        __builtin_bit_cast(bfv8, a), __builtin_bit_cast(bfv8, b), c, 0, 0, 0);
}

// async global->LDS, 16B per lane; dest is wave-uniform base + lane*16
static __device__ __forceinline__ void gl_lds16(const unsigned short* g, unsigned short* l) {
    __builtin_amdgcn_global_load_lds(
        (const __attribute__((address_space(1))) unsigned int*)g,
        (__attribute__((address_space(3))) unsigned int*)l, 16, 0, 0);
}

// ---------------- K1: GroupNorm (blocks 0..255) + w1 cvt (blocks 256..447) ----------------
__global__ __launch_bounds__(512) void k_gn_w1(const float* __restrict__ x,
                                               const float* __restrict__ gw,
                                               const float* __restrict__ gb,
                                               const float* __restrict__ w1,
                                               unsigned short* __restrict__ xnT,
                                               unsigned short* __restrict__ w1b) {
    int tid = threadIdx.x;
    if (blockIdx.x >= 256) {   // w1 fp32 -> bf16
        int i = ((blockIdx.x - 256) * 512 + tid) * 8;
        f32x4 a = *(const f32x4*)(w1 + i);
        f32x4 b = *(const f32x4*)(w1 + i + 4);
        u16x8 o;
#pragma unroll
        for (int j = 0; j < 4; ++j) { o[j] = f2bf(a[j]); o[4 + j] = f2bf(b[j]); }
        *(u16x8*)(w1b + i) = o;
        return;
    }
    int b = blockIdx.x >> 5, g = blockIdx.x & 31;
    int half = tid >> 8, tl = tid & 255;
    int t4 = tl * 4;
    const float* xb = x + ((size_t)(b * NC + g * NGC + half * 8)) * NT;

    f32x4 vv[8];
    float s = 0.f, ss = 0.f;
#pragma unroll
    for (int cc = 0; cc < 8; ++cc) {
        f32x4 v = *(const f32x4*)(xb + cc * NT + t4);
        vv[cc] = v;
#pragma unroll
        for (int i = 0; i < 4; ++i) { s += v[i]; ss += v[i] * v[i]; }
    }
#pragma unroll
    for (int off = 1; off < 64; off <<= 1) { s += __shfl_xor(s, off); ss += __shfl_xor(ss, off); }
    __shared__ float rs_[8], rss[8];
    int w = tid >> 6;
    if ((tid & 63) == 0) { rs_[w] = s; rss[w] = ss; }
    __syncthreads();
    s = 0.f; ss = 0.f;
#pragma unroll
    for (int i = 0; i < 8; ++i) { s += rs_[i]; ss += rss[i]; }
    float mu  = s * (1.f / 16384.f);
    float var = ss * (1.f / 16384.f) - mu * mu;
    float rstd = rsqrtf(var + 1e-5f);

    float wgt[8], bia[8];
#pragma unroll
    for (int cc = 0; cc < 8; ++cc) {
        float ww = gw[g * NGC + half * 8 + cc] * rstd;
        wgt[cc] = ww;
        bia[cc] = gb[g * NGC + half * 8 + cc] - mu * ww;
    }
#pragma unroll
    for (int i = 0; i < 4; ++i) {
        unsigned short o[8];
#pragma unroll
        for (int cc = 0; cc < 8; ++cc) o[cc] = f2bf(vv[cc][i] * wgt[cc] + bia[cc]);
        unsigned short* dst = xnT + ((size_t)(b * NT + t4 + i)) * NC + g * NGC + half * 8;
        *(u16x8*)dst = *(u16x8*)o;
    }
}

// ---------------- K2: QKV GEMM (BK=32, 32KB LDS -> 4 blocks/CU) ----------------
__global__ __launch_bounds__(256) void k_qkv_gemm(const unsigned short* __restrict__ w1b,
                                                  const unsigned short* __restrict__ xnT,
                                                  const float* __restrict__ b1,
                                                  unsigned short* __restrict__ q_t,
                                                  unsigned short* __restrict__ k_t,
                                                  unsigned short* __restrict__ vbuf) {
    __shared__ unsigned short As[2 * 128 * 32];   // 16KB
    __shared__ unsigned short Bs[2 * 128 * 32];   // 16KB
    int bid = blockIdx.x;
    int lbid = (bid & 7) * 96 + (bid >> 3);   // XCD x owns batch x (768 = 8*96, bijective)
    int bb = lbid / 96;
    int rr_ = lbid % 96;
    int tm = rr_ >> 3, tn = rr_ & 7;
    int tid = threadIdx.x;
    int l = tid & 63, w = tid >> 6;
    int wm = w >> 1, wn = w & 1;
    int ll = l & 15, lg = l >> 4;

    const unsigned short* Ag = w1b + (size_t)(tm * 128) * NC;
    const unsigned short* Bg = xnT + (size_t)(bb * NT + tn * 128) * NC;

    int srow = l >> 2;
    int sslot = (l & 3) ^ ((l >> 3) & 3);   // == (l&3) ^ ((row>>1)&3)

    auto STAGE = [&](int k0, int buf) {
        unsigned short* dA = As + buf * 4096 + w * 1024;
        unsigned short* dB = Bs + buf * 4096 + w * 1024;
#pragma unroll
        for (int i = 0; i < 2; ++i) {
            int row = w * 32 + i * 16 + srow;
            gl_lds16(Ag + (size_t)row * NC + k0 + sslot * 8, dA + i * 512);
            gl_lds16(Bg + (size_t)row * NC + k0 + sslot * 8, dB + i * 512);
        }
    };

    f32x4 acc[4][4] = {};
    STAGE(0, 0);
    __syncthreads();
    int cur = 0;
    int rsw = (ll >> 1) & 3;   // read-side swizzle == (row>>1)&3 for row = 16m+ll
    for (int ks = 0; ks < 16; ++ks) {
        if (ks < 15) STAGE((ks + 1) * 32, cur ^ 1);
        const char* Ac = (const char*)(As + cur * 4096);
        const char* Bc = (const char*)(Bs + cur * 4096);
        u16x8 af[4], bf[4];
#pragma unroll
        for (int m = 0; m < 4; ++m) {
            int row = wm * 64 + m * 16 + ll;
            af[m] = *(const u16x8*)(Ac + row * 64 + ((lg ^ rsw) * 16));
        }
#pragma unroll
        for (int n = 0; n < 4; ++n) {
            int row = wn * 64 + n * 16 + ll;
            bf[n] = *(const u16x8*)(Bc + row * 64 + ((lg ^ rsw) * 16));
        }
#pragma unroll
        for (int m = 0; m < 4; ++m)
#pragma unroll
            for (int n = 0; n < 4; ++n)
                acc[m][n] = mfma_bf16(af[m], bf[n], acc[m][n]);
        __syncthreads();
        cur ^= 1;
    }

    if (tm < 8) {   // q or k: write [b][h][t][c]
        int qk = tm >> 2;
        int h = (tm & 3) * 2 + wm;
        float sc = qk ? 1.f : 0.125f * 1.44269504088896f;  // q: ch^-0.5 * log2(e)
        int obase = tm * 128 + wm * 64;
        unsigned short* dst = (qk ? k_t : q_t) + ((size_t)(bb * 8 + h)) * NT * NCH;
#pragma unroll
        for (int m = 0; m < 4; ++m) {
#pragma unroll
            for (int n = 0; n < 4; ++n) {
                int t = tn * 128 + wn * 64 + n * 16 + ll;
                u16x4 pk;
#pragma unroll
                for (int r = 0; r < 4; ++r)
                    pk[r] = f2bf((acc[m][n][r] + b1[obase + m * 16 + lg * 4 + r]) * sc);
                *(u16x4*)(dst + (size_t)t * NCH + m * 16 + lg * 4) = pk;
            }
        }
    } else {        // v: natural [b][vc][t]
        int vcb = (tm - 8) * 128 + wm * 64;
#pragma unroll
        for (int m = 0; m < 4; ++m)
#pragma unroll
            for (int r = 0; r < 4; ++r) {
                int vc = vcb + m * 16 + lg * 4 + r;
                float bias = b1[1024 + vc];
#pragma unroll
                for (int n = 0; n < 4; ++n) {
                    int t = tn * 128 + wn * 64 + n * 16 + ll;
                    vbuf[(size_t)(bb * NC + vc) * NT + t] = f2bf(acc[m][n][r] + bias);
                }
            }
    }
}

// ---------------- K3: attention v7 (64 q-rows/wave -> K/V LDS bytes per flop halved) ----------------
// block = (b, h, 256-query tile), 4 waves x 64 q-rows; grid 256 (1 block/CU).
// K [s][c] and V [c][s] 64-key tiles double-buffered via global_load_lds (src-swizzled);
// each wave's 16KB tile read now feeds 2x the MFMA work vs 32-row waves.
// Swapped QK (S^T), packed b64 P writes, exp2 with log2e folded into q. No max subtraction.
#define SW1B(r) (((r) & 7) << 4)
__global__ __launch_bounds__(256) void k_attn(const unsigned short* __restrict__ q_t,
                                              const unsigned short* __restrict__ k_t,
                                              const unsigned short* __restrict__ vbuf,
                                              const float* __restrict__ x,
                                              float* __restrict__ out) {
    __shared__ unsigned char smem[65536];
    unsigned short* sK = (unsigned short*)smem;            // [2][64 s][64 c] bf16, 16KB
    unsigned short* sV = (unsigned short*)(smem + 16384);  // [2][64 c][64 s] bf16, 16KB
    unsigned short* sP = (unsigned short*)(smem + 32768);  // [4 w][64 t][64 s] bf16, 32KB

    int lbid = ((blockIdx.x & 7) << 5) | (blockIdx.x >> 3);  // XCD x hosts batch x
    int b  = lbid >> 5;
    int h  = (lbid >> 2) & 7;
    int qt = lbid & 3;
    int t0 = qt * 256;

    int tid = threadIdx.x;
    int l = tid & 63, w = tid >> 6;
    int ll = l & 15, lg = l >> 4;
    int rl = l >> 3, sl = l & 7;
    int ssl = sl ^ rl;

    const unsigned short* Qg = q_t + ((size_t)((b * 8 + h) * NT + t0 + w * 64)) * NCH;
    const unsigned short* Kg = k_t + ((size_t)(b * 8 + h)) * NT * NCH;
    const unsigned short* Vg = vbuf + ((size_t)(b * NC + h * NCH)) * NT;

    u16x8 aq[4][2];   // Q for 64 rows: t = m*16+ll
#pragma unroll
    for (int m = 0; m < 4; ++m)
#pragma unroll
        for (int kk = 0; kk < 2; ++kk)
            aq[m][kk] = *(const u16x8*)(Qg + (m * 16 + ll) * NCH + kk * 32 + lg * 8);

    f32x4 acc_o[4][4] = {};
    float rs[4] = {};

    auto STAGE = [&](int s0, int buf) {
        unsigned short* dK = sK + buf * 4096 + w * 1024;
        unsigned short* dV = sV + buf * 4096 + w * 1024;
#pragma unroll
        for (int i = 0; i < 2; ++i) {
            int row = w * 16 + i * 8 + rl;    // row&7 == rl
            gl_lds16(Kg + (size_t)(s0 + row) * NCH + ssl * 8, dK + i * 512);
            gl_lds16(Vg + (size_t)row * NT + s0 + ssl * 8, dV + i * 512);
        }
    };

    STAGE(0, 0);
    __syncthreads();

    char* sPw = (char*)(sP + w * 4096);   // per-wave [64 t][64 s] bf16 (8KB)
    int cur = 0;
    for (int tile = 0; tile < 16; ++tile) {
        if (tile < 15) STAGE((tile + 1) * 64, cur ^ 1);
        const char* Kc = (const char*)(sK + cur * 4096);
        const char* Vc = (const char*)(sV + cur * 4096);

        // S^T = K Q^T: lane holds col t = m*16+ll, rows s = j*16 + lg*4 + r
        f32x4 sc_[4][4];
#pragma unroll
        for (int j = 0; j < 4; ++j) {
            int row = j * 16 + ll;
            int sw = SW1B(row);
            u16x8 b0 = *(const u16x8*)(Kc + row * 128 + ((lg * 16) ^ sw));
            u16x8 b1v = *(const u16x8*)(Kc + row * 128 + ((64 + lg * 16) ^ sw));
#pragma unroll
            for (int m = 0; m < 4; ++m) {
                f32x4 z = {0.f, 0.f, 0.f, 0.f};
                sc_[m][j] = mfma_bf16(b1v, aq[m][1], mfma_bf16(b0, aq[m][0], z));
            }
        }

        // P = exp2(S); packed 8B writes; scalar rowsum per t-column
#pragma unroll
        for (int m = 0; m < 4; ++m) {
            int t = m * 16 + ll;
            int sw = (t & 7) << 4;
#pragma unroll
            for (int j = 0; j < 4; ++j) {
                float p0 = __builtin_amdgcn_exp2f(sc_[m][j][0]);
                float p1 = __builtin_amdgcn_exp2f(sc_[m][j][1]);
                float p2 = __builtin_amdgcn_exp2f(sc_[m][j][2]);
                float p3 = __builtin_amdgcn_exp2f(sc_[m][j][3]);
                rs[m] += (p0 + p1) + (p2 + p3);
                u16x4 pk = {f2bf(p0), f2bf(p1), f2bf(p2), f2bf(p3)};
                *(u16x4*)(sPw + t * 128 + ((j * 32 + lg * 8) ^ sw)) = pk;
            }
        }

        // O += P V^T: D[t 64][c 64] per wave
        u16x8 ap[4][2];
#pragma unroll
        for (int m = 0; m < 4; ++m) {
            int t = m * 16 + ll;
            int sw = (t & 7) << 4;
#pragma unroll
            for (int kk = 0; kk < 2; ++kk)
                ap[m][kk] = *(const u16x8*)(sPw + t * 128 + ((kk * 64 + lg * 16) ^ sw));
        }
#pragma unroll
        for (int n = 0; n < 4; ++n) {
            int row = n * 16 + ll;
            int sw = SW1B(row);
#pragma unroll
            for (int kk = 0; kk < 2; ++kk) {
                u16x8 bv = *(const u16x8*)(Vc + row * 128 + ((kk * 64 + lg * 16) ^ sw));
#pragma unroll
                for (int m = 0; m < 4; ++m)
                    acc_o[m][n] = mfma_bf16(ap[m][kk], bv, acc_o[m][n]);
            }
        }
        __syncthreads();   // drains staging vmcnt + guards buffer swap
        cur ^= 1;
    }

    // rowsum: rs[m] is partial over this lane's s-rows; reduce across lg replicas
    float rinv[4][4];
#pragma unroll
    for (int m = 0; m < 4; ++m) {
        float s = rs[m];
        s += __shfl_xor(s, 16);
        s += __shfl_xor(s, 32);
#pragma unroll
        for (int r = 0; r < 4; ++r)
            rinv[m][r] = 1.f / __shfl(s, (l & 48) + lg * 4 + r);
    }

    // epilogue: O -> per-wave LDS [c 64][t 64] f32 (16KB, swizzled), then coalesced out+residual
    char* sO = (char*)(smem + w * 16384);   // all of smem dead after final barrier; disjoint per wave
#pragma unroll
    for (int m = 0; m < 4; ++m)
#pragma unroll
        for (int n = 0; n < 4; ++n) {
            int c = n * 16 + ll;
            f32x4 o4;
#pragma unroll
            for (int r = 0; r < 4; ++r) o4[r] = acc_o[m][n][r] * rinv[m][r];
            *(f32x4*)(sO + c * 256 + ((m * 64 + lg * 16) ^ ((c & 7) << 4))) = o4;
        }
#pragma unroll
    for (int m2 = 0; m2 < 2; ++m2)
#pragma unroll
        for (int i2 = 0; i2 < 8; ++i2) {
            int c = i2 * 8 + rl;
            f32x4 o4 = *(const f32x4*)(sO + c * 256 + ((m2 * 128 + sl * 16) ^ ((c & 7) << 4)));
            size_t gidx = ((size_t)(b * NC + h * NCH + c)) * NT + t0 + w * 64 + m2 * 32 + sl * 4;
            f32x4 xv = *(const f32x4*)(x + gidx);
#pragma unroll
            for (int q = 0; q < 4; ++q) o4[q] += xv[q];
            *(f32x4*)(out + gidx) = o4;
        }
}

extern "C" void kernel_launch(void* const* d_in, const int* in_sizes, int n_in,
                              void* d_out, int out_size, void* d_ws, size_t ws_size,
                              hipStream_t stream) {
    (void)in_sizes; (void)n_in; (void)out_size; (void)ws_size;
    const float* x  = (const float*)d_in[0];
    const float* gw = (const float*)d_in[1];
    const float* gb = (const float*)d_in[2];
    const float* w1 = (const float*)d_in[3];
    const float* b1 = (const float*)d_in[4];
    float* out = (float*)d_out;

    char* ws = (char*)d_ws;
    unsigned short* w1b  = (unsigned short*)(ws);                        // 1.5 MB
    unsigned short* xnT  = (unsigned short*)(ws + (size_t)(2u << 20));   // 8.39 MB
    unsigned short* q_t  = (unsigned short*)(ws + (size_t)(11u << 20));  // 8.39 MB
    unsigned short* k_t  = (unsigned short*)(ws + (size_t)(20u << 20));  // 8.39 MB
    unsigned short* vbuf = (unsigned short*)(ws + (size_t)(29u << 20));  // 8.39 MB

    k_gn_w1<<<dim3(448), dim3(512), 0, stream>>>(x, gw, gb, w1, xnT, w1b);
    k_qkv_gemm<<<dim3(768), dim3(256), 0, stream>>>(w1b, xnT, b1, q_t, k_t, vbuf);
    k_attn<<<dim3(256), dim3(256), 0, stream>>>(q_t, k_t, vbuf, x, out);
}

// Round 10
// 65.689 us; speedup vs baseline: 1.2029x; 1.1443x over previous
//
#include <hip/hip_runtime.h>
#include <hip/hip_bf16.h>

#define NB 8
#define NC 512
#define NT 1024
#define NHEADS 8
#define NCH 64
#define NGROUPS 32
#define NGC 16   // channels per group

typedef __attribute__((ext_vector_type(4))) unsigned short u16x4;
typedef __attribute__((ext_vector_type(8))) unsigned short u16x8;
typedef __attribute__((ext_vector_type(4))) float f32x4;
typedef __attribute__((ext_vector_type(8))) __bf16 bfv8;

// hardware f32->bf16 RNE (single v_cvt op; compiler packs pairs to v_cvt_pk_bf16_f32)
static __device__ __forceinline__ unsigned short f2bf(float f) {
    __bf16 h = (__bf16)f;
    return __builtin_bit_cast(unsigned short, h);
}

static __device__ __forceinline__ f32x4 mfma_bf16(u16x8 a, u16x8 b, f32x4 c) {
    return __builtin_amdgcn_mfma_f32_16x16x32_bf16(
        __builtin_bit_cast(bfv8, a), __builtin_bit_cast(bfv8, b), c, 0, 0, 0);
}

// async global->LDS, 16B per lane; dest is wave-uniform base + lane*16
static __device__ __forceinline__ void gl_lds16(const unsigned short* g, unsigned short* l) {
    __builtin_amdgcn_global_load_lds(
        (const __attribute__((address_space(1))) unsigned int*)g,
        (__attribute__((address_space(3))) unsigned int*)l, 16, 0, 0);
}

// ---------------- K1: GroupNorm (blocks 0..255) + w1 cvt (blocks 256..447) ----------------
__global__ __launch_bounds__(512) void k_gn_w1(const float* __restrict__ x,
                                               const float* __restrict__ gw,
                                               const float* __restrict__ gb,
                                               const float* __restrict__ w1,
                                               unsigned short* __restrict__ xnT,
                                               unsigned short* __restrict__ w1b) {
    int tid = threadIdx.x;
    if (blockIdx.x >= 256) {   // w1 fp32 -> bf16
        int i = ((blockIdx.x - 256) * 512 + tid) * 8;
        f32x4 a = *(const f32x4*)(w1 + i);
        f32x4 b = *(const f32x4*)(w1 + i + 4);
        u16x8 o;
#pragma unroll
        for (int j = 0; j < 4; ++j) { o[j] = f2bf(a[j]); o[4 + j] = f2bf(b[j]); }
        *(u16x8*)(w1b + i) = o;
        return;
    }
    int b = blockIdx.x >> 5, g = blockIdx.x & 31;
    int half = tid >> 8, tl = tid & 255;
    int t4 = tl * 4;
    const float* xb = x + ((size_t)(b * NC + g * NGC + half * 8)) * NT;

    f32x4 vv[8];
    float s = 0.f, ss = 0.f;
#pragma unroll
    for (int cc = 0; cc < 8; ++cc) {
        f32x4 v = *(const f32x4*)(xb + cc * NT + t4);
        vv[cc] = v;
#pragma unroll
        for (int i = 0; i < 4; ++i) { s += v[i]; ss += v[i] * v[i]; }
    }
#pragma unroll
    for (int off = 1; off < 64; off <<= 1) { s += __shfl_xor(s, off); ss += __shfl_xor(ss, off); }
    __shared__ float rs_[8], rss[8];
    int w = tid >> 6;
    if ((tid & 63) == 0) { rs_[w] = s; rss[w] = ss; }
    __syncthreads();
    s = 0.f; ss = 0.f;
#pragma unroll
    for (int i = 0; i < 8; ++i) { s += rs_[i]; ss += rss[i]; }
    float mu  = s * (1.f / 16384.f);
    float var = ss * (1.f / 16384.f) - mu * mu;
    float rstd = rsqrtf(var + 1e-5f);

    float wgt[8], bia[8];
#pragma unroll
    for (int cc = 0; cc < 8; ++cc) {
        float ww = gw[g * NGC + half * 8 + cc] * rstd;
        wgt[cc] = ww;
        bia[cc] = gb[g * NGC + half * 8 + cc] - mu * ww;
    }
#pragma unroll
    for (int i = 0; i < 4; ++i) {
        unsigned short o[8];
#pragma unroll
        for (int cc = 0; cc < 8; ++cc) o[cc] = f2bf(vv[cc][i] * wgt[cc] + bia[cc]);
        unsigned short* dst = xnT + ((size_t)(b * NT + t4 + i)) * NC + g * NGC + half * 8;
        *(u16x8*)dst = *(u16x8*)o;
    }
}

// ---------------- K2: QKV GEMM (BK=64, R7 config — evidence: BK32 was ~6us slower) ----------------
__global__ __launch_bounds__(256) void k_qkv_gemm(const unsigned short* __restrict__ w1b,
                                                  const unsigned short* __restrict__ xnT,
                                                  const float* __restrict__ b1,
                                                  unsigned short* __restrict__ q_t,
                                                  unsigned short* __restrict__ k_t,
                                                  unsigned short* __restrict__ vbuf) {
    __shared__ unsigned short As[2 * 128 * 64];   // 32KB
    __shared__ unsigned short Bs[2 * 128 * 64];   // 32KB
    int bid = blockIdx.x;
    int lbid = (bid & 7) * 96 + (bid >> 3);   // XCD x owns batch x (768 = 8*96, bijective)
    int bb = lbid / 96;
    int rr_ = lbid % 96;
    int tm = rr_ >> 3, tn = rr_ & 7;
    int tid = threadIdx.x;
    int l = tid & 63, w = tid >> 6;
    int wm = w >> 1, wn = w & 1;
    int ll = l & 15, lg = l >> 4;
    int rl = l >> 3, sl = l & 7;
    int ssl = sl ^ rl;

    const unsigned short* Ag = w1b + (size_t)(tm * 128) * NC;
    const unsigned short* Bg = xnT + (size_t)(bb * NT + tn * 128) * NC;

    auto STAGE = [&](int k0, int buf) {
        unsigned short* dA = As + buf * 8192 + w * 32 * 64;
        unsigned short* dB = Bs + buf * 8192 + w * 32 * 64;
#pragma unroll
        for (int i = 0; i < 4; ++i) {
            int row = w * 32 + i * 8 + rl;    // row&7 == rl
            gl_lds16(Ag + (size_t)row * NC + k0 + ssl * 8, dA + i * 512);
            gl_lds16(Bg + (size_t)row * NC + k0 + ssl * 8, dB + i * 512);
        }
    };

    f32x4 acc[4][4] = {};
    STAGE(0, 0);
    __syncthreads();
    int cur = 0;
    for (int ks = 0; ks < 8; ++ks) {
        if (ks < 7) STAGE((ks + 1) * 64, cur ^ 1);
        const char* Ac = (const char*)(As + cur * 8192);
        const char* Bc = (const char*)(Bs + cur * 8192);
#pragma unroll
        for (int kk = 0; kk < 2; ++kk) {
            u16x8 af[4], bf[4];
#pragma unroll
            for (int m = 0; m < 4; ++m) {
                int row = wm * 64 + m * 16 + ll;
                af[m] = *(const u16x8*)(Ac + row * 128 + ((kk * 64 + lg * 16) ^ ((row & 7) << 4)));
            }
#pragma unroll
            for (int n = 0; n < 4; ++n) {
                int row = wn * 64 + n * 16 + ll;
                bf[n] = *(const u16x8*)(Bc + row * 128 + ((kk * 64 + lg * 16) ^ ((row & 7) << 4)));
            }
#pragma unroll
            for (int m = 0; m < 4; ++m)
#pragma unroll
                for (int n = 0; n < 4; ++n)
                    acc[m][n] = mfma_bf16(af[m], bf[n], acc[m][n]);
        }
        __syncthreads();
        cur ^= 1;
    }

    if (tm < 8) {   // q or k: write [b][h][t][c]
        int qk = tm >> 2;
        int h = (tm & 3) * 2 + wm;
        float sc = qk ? 1.f : 0.125f * 1.44269504088896f;  // q: ch^-0.5 * log2(e)
        int obase = tm * 128 + wm * 64;
        unsigned short* dst = (qk ? k_t : q_t) + ((size_t)(bb * 8 + h)) * NT * NCH;
#pragma unroll
        for (int m = 0; m < 4; ++m) {
#pragma unroll
            for (int n = 0; n < 4; ++n) {
                int t = tn * 128 + wn * 64 + n * 16 + ll;
                u16x4 pk;
#pragma unroll
                for (int r = 0; r < 4; ++r)
                    pk[r] = f2bf((acc[m][n][r] + b1[obase + m * 16 + lg * 4 + r]) * sc);
                *(u16x4*)(dst + (size_t)t * NCH + m * 16 + lg * 4) = pk;
            }
        }
    } else {        // v: natural [b][vc][t]
        int vcb = (tm - 8) * 128 + wm * 64;
#pragma unroll
        for (int m = 0; m < 4; ++m)
#pragma unroll
            for (int r = 0; r < 4; ++r) {
                int vc = vcb + m * 16 + lg * 4 + r;
                float bias = b1[1024 + vc];
#pragma unroll
                for (int n = 0; n < 4; ++n) {
                    int t = tn * 128 + wn * 64 + n * 16 + ll;
                    vbuf[(size_t)(bb * NC + vc) * NT + t] = f2bf(acc[m][n][r] + bias);
                }
            }
    }
}

// ---------------- K3: attention v8 (v5 + triple-buffer K/V, counted vmcnt, no drain) ----------------
// block = (b, h, 128-query tile); 4 waves x 32 q-rows. K/V 64-key tiles TRIPLE-buffered:
// stage(T+3) issued after "done reading buf" barrier; tile entry waits vmcnt(8)
// (= stages for T+1,T+2 in flight, 4 gl_lds/wave each) — prefetch never drains (T3/T4).
// Swapped-QK S^T, packed b64 P writes, exp2 (log2e folded into q), no max subtraction.
#define SW1B(r) (((r) & 7) << 4)
__global__ __launch_bounds__(256) void k_attn(const unsigned short* __restrict__ q_t,
                                              const unsigned short* __restrict__ k_t,
                                              const unsigned short* __restrict__ vbuf,
                                              const float* __restrict__ x,
                                              float* __restrict__ out) {
    __shared__ unsigned char smem[65536];
    unsigned short* sK = (unsigned short*)smem;            // [3][64][64] bf16, 24KB
    unsigned short* sV = (unsigned short*)(smem + 24576);  // [3][64][64] bf16, 24KB
    unsigned short* sP = (unsigned short*)(smem + 49152);  // [4][32][64] bf16, 16KB

    int lbid = ((blockIdx.x & 7) << 6) | (blockIdx.x >> 3);  // XCD x hosts batch x
    int b  = lbid >> 6;
    int h  = (lbid >> 3) & 7;
    int qt = lbid & 7;
    int t0 = qt * 128;

    int tid = threadIdx.x;
    int l = tid & 63, w = tid >> 6;
    int ll = l & 15, lg = l >> 4;
    int rl = l >> 3, sl = l & 7;
    int ssl = sl ^ rl;

    const unsigned short* Qg = q_t + ((size_t)((b * 8 + h) * NT + t0 + w * 32)) * NCH;
    const unsigned short* Kg = k_t + ((size_t)(b * 8 + h)) * NT * NCH;
    const unsigned short* Vg = vbuf + ((size_t)(b * NC + h * NCH)) * NT;

    u16x8 aq[2][2];
#pragma unroll
    for (int m = 0; m < 2; ++m)
#pragma unroll
        for (int kk = 0; kk < 2; ++kk)
            aq[m][kk] = *(const u16x8*)(Qg + (m * 16 + ll) * NCH + kk * 32 + lg * 8);

    f32x4 acc_o[2][4] = {};
    float rs[2] = {};

    auto STAGE = [&](int s0, int buf) {   // 4 gl_lds per wave (2 K + 2 V)
        unsigned short* dK = sK + buf * 4096 + w * 1024;
        unsigned short* dV = sV + buf * 4096 + w * 1024;
#pragma unroll
        for (int i = 0; i < 2; ++i) {
            int row = w * 16 + i * 8 + rl;    // row&7 == rl
            gl_lds16(Kg + (size_t)(s0 + row) * NCH + ssl * 8, dK + i * 512);
            gl_lds16(Vg + (size_t)row * NT + s0 + ssl * 8, dV + i * 512);
        }
    };

    STAGE(0, 0);
    STAGE(64, 1);
    STAGE(128, 2);

    char* sPw = (char*)(sP + w * 2048);   // per-wave [32 t][64 s] bf16 (4KB)
    for (int tile = 0; tile < 16; ++tile) {
        // wait for THIS tile's stages (oldest); keep T+1,T+2 stages in flight
        if (tile < 14)       asm volatile("s_waitcnt vmcnt(8)" ::: "memory");
        else if (tile == 14) asm volatile("s_waitcnt vmcnt(4)" ::: "memory");
        else                 asm volatile("s_waitcnt vmcnt(0)" ::: "memory");
        __builtin_amdgcn_s_barrier();          // all waves' stages for this tile landed
        __builtin_amdgcn_sched_barrier(0);

        int cur = tile % 3;
        const char* Kc = (const char*)(sK + cur * 4096);
        const char* Vc = (const char*)(sV + cur * 4096);

        // S^T = K Q^T (swapped operands): lane holds col t = m*16+ll, rows s = j*16+lg*4+r
        f32x4 sc_[2][4];
#pragma unroll
        for (int j = 0; j < 4; ++j) {
            int row = j * 16 + ll;
            int sw = SW1B(row);
            u16x8 b0 = *(const u16x8*)(Kc + row * 128 + ((lg * 16) ^ sw));
            u16x8 b1v = *(const u16x8*)(Kc + row * 128 + ((64 + lg * 16) ^ sw));
            f32x4 z = {0.f, 0.f, 0.f, 0.f};
            sc_[0][j] = mfma_bf16(b1v, aq[0][1], mfma_bf16(b0, aq[0][0], z));
            sc_[1][j] = mfma_bf16(b1v, aq[1][1], mfma_bf16(b0, aq[1][0], z));
        }

        // P = exp2(S); 4 consecutive s per reg -> packed 8B write; scalar rowsum
#pragma unroll
        for (int m = 0; m < 2; ++m) {
            int t = m * 16 + ll;
            int sw = (t & 7) << 4;
#pragma unroll
            for (int j = 0; j < 4; ++j) {
                float p0 = __builtin_amdgcn_exp2f(sc_[m][j][0]);
                float p1 = __builtin_amdgcn_exp2f(sc_[m][j][1]);
                float p2 = __builtin_amdgcn_exp2f(sc_[m][j][2]);
                float p3 = __builtin_amdgcn_exp2f(sc_[m][j][3]);
                rs[m] += (p0 + p1) + (p2 + p3);
                u16x4 pk = {f2bf(p0), f2bf(p1), f2bf(p2), f2bf(p3)};
                *(u16x4*)(sPw + t * 128 + ((j * 32 + lg * 8) ^ sw)) = pk;
            }
        }

        // O += P V^T (D[t 32][c 64]); P reads == A-frag layout directly
        u16x8 ap[2][2];
#pragma unroll
        for (int m = 0; m < 2; ++m) {
            int t = m * 16 + ll;
            int sw = (t & 7) << 4;
#pragma unroll
            for (int kk = 0; kk < 2; ++kk)
                ap[m][kk] = *(const u16x8*)(sPw + t * 128 + ((kk * 64 + lg * 16) ^ sw));
        }
#pragma unroll
        for (int n = 0; n < 4; ++n) {
            int row = n * 16 + ll;
            int sw = SW1B(row);
#pragma unroll
            for (int kk = 0; kk < 2; ++kk) {
                u16x8 bv = *(const u16x8*)(Vc + row * 128 + ((kk * 64 + lg * 16) ^ sw));
                acc_o[0][n] = mfma_bf16(ap[0][kk], bv, acc_o[0][n]);
                acc_o[1][n] = mfma_bf16(ap[1][kk], bv, acc_o[1][n]);
            }
        }

        __builtin_amdgcn_sched_barrier(0);
        __builtin_amdgcn_s_barrier();          // all waves done reading buf cur
        if (tile < 13) STAGE((tile + 3) * 64, cur);   // refill the just-freed buffer
    }

    // rowsum: lane holds rs for t = m*16+ll; reduce across the 4 lg replicas
    float rinv[2][4];
#pragma unroll
    for (int m = 0; m < 2; ++m) {
        float s = rs[m];
        s += __shfl_xor(s, 16);
        s += __shfl_xor(s, 32);
        // redistribute to PV-accumulator lanes: t = m*16 + lg*4 + r lives at ll = lg*4+r
#pragma unroll
        for (int r = 0; r < 4; ++r)
            rinv[m][r] = 1.f / __shfl(s, (l & 48) + lg * 4 + r);
    }

    // epilogue: O -> per-wave LDS [c 64][t 32] f32 (swizzled), then coalesced out+residual
    char* sO = (char*)(smem + w * 8192);   // reuses sK/sV (all reads done at final barrier)
#pragma unroll
    for (int m = 0; m < 2; ++m)
#pragma unroll
        for (int n = 0; n < 4; ++n) {
            int c = n * 16 + ll;
            f32x4 o4;
#pragma unroll
            for (int r = 0; r < 4; ++r) o4[r] = acc_o[m][n][r] * rinv[m][r];
            *(f32x4*)(sO + c * 128 + ((m * 64 + lg * 16) ^ SW1B(c))) = o4;
        }
#pragma unroll
    for (int i2 = 0; i2 < 8; ++i2) {
        int c = i2 * 8 + rl;
        f32x4 o4 = *(const f32x4*)(sO + c * 128 + ((sl * 16) ^ SW1B(c)));
        size_t gidx = ((size_t)(b * NC + h * NCH + c)) * NT + t0 + w * 32 + sl * 4;
        f32x4 xv = *(const f32x4*)(x + gidx);
#pragma unroll
        for (int q = 0; q < 4; ++q) o4[q] += xv[q];
        *(f32x4*)(out + gidx) = o4;
    }
}

extern "C" void kernel_launch(void* const* d_in, const int* in_sizes, int n_in,
                              void* d_out, int out_size, void* d_ws, size_t ws_size,
                              hipStream_t stream) {
    (void)in_sizes; (void)n_in; (void)out_size; (void)ws_size;
    const float* x  = (const float*)d_in[0];
    const float* gw = (const float*)d_in[1];
    const float* gb = (const float*)d_in[2];
    const float* w1 = (const float*)d_in[3];
    const float* b1 = (const float*)d_in[4];
    float* out = (float*)d_out;

    char* ws = (char*)d_ws;
    unsigned short* w1b  = (unsigned short*)(ws);                        // 1.5 MB
    unsigned short* xnT  = (unsigned short*)(ws + (size_t)(2u << 20));   // 8.39 MB
    unsigned short* q_t  = (unsigned short*)(ws + (size_t)(11u << 20));  // 8.39 MB
    unsigned short* k_t  = (unsigned short*)(ws + (size_t)(20u << 20));  // 8.39 MB
    unsigned short* vbuf = (unsigned short*)(ws + (size_t)(29u << 20));  // 8.39 MB

    k_gn_w1<<<dim3(448), dim3(512), 0, stream>>>(x, gw, gb, w1, xnT, w1b);
    k_qkv_gemm<<<dim3(768), dim3(256), 0, stream>>>(w1b, xnT, b1, q_t, k_t, vbuf);
    k_attn<<<dim3(512), dim3(256), 0, stream>>>(q_t, k_t, vbuf, x, out);
}